// Round 7
// baseline (668.959 us; speedup 1.0000x reference)
//
#include <hip/hip_runtime.h>
#include <math.h>

// Problem constants
#define B_    64
#define MAXT  511
#define TP1   512
#define S_    1024
#define H_    4096
#define M_TOTAL (B_*TP1)   // 32768 rows
#define NITER (S_/32)      // 32 K-iterations

typedef __attribute__((ext_vector_type(8))) short  short8;   // 8 bf16 = 4 VGPRs (MFMA A/B frag)
typedef __attribute__((ext_vector_type(4))) float  float4v;  // MFMA C/D frag

// ---- workspace layout (bytes) ----
// zbuf [0, 512KB) ; cnt [512KB, +1KB) ; Sb at SBF_OFF ; W1T after.
// First memset zeroes [0, 0x81000) = zbuf + cnt scratch page.
#define ZSCRATCH_BYTES 0x81000
#define CNT_OFF    0x80000
#define SBF_OFF    0x81000
#define SBF_BYTES  ((size_t)M_TOTAL*S_*2)
#define W1T_OFF    (SBF_OFF + SBF_BYTES)

static __device__ __forceinline__ unsigned short f2bf(float f) {
    unsigned int u = __float_as_uint(f);
    u = u + 0x7fffu + ((u >> 16) & 1u);   // round-to-nearest-even
    return (unsigned short)(u >> 16);
}

// in-wave exclusive-prefix helper: returns inclusive scan of lengths[lane]
static __device__ __forceinline__ int wave_scan_len(const int* lengths, int lane, int& v) {
    v = lengths[lane];
    int x = v;
#pragma unroll
    for (int d = 1; d < 64; d <<= 1) {
        int y = __shfl_up(x, d);
        if (lane >= d) x += y;
    }
    return x;   // inclusive
}

// ---- merged pre-pass: s -> COMPACTED bf16 rows + W1 -> W1T bf16 ----
// offs self-computed per wave (offsets_kernel deleted: one fewer dispatch).
__global__ __launch_bounds__(256) void prep_kernel(const float* __restrict__ s,
                                                   const float* __restrict__ W1,
                                                   const int*   __restrict__ lengths,
                                                   unsigned short* __restrict__ Sb,
                                                   unsigned short* __restrict__ W1T) {
    int bid = blockIdx.x;
    if (bid < 16384) {
        int lane = threadIdx.x & 63;
        int lv; int lx = wave_scan_len(lengths, lane, lv);
        int row = 2 * bid + (threadIdx.x >> 7);          // wave-uniform row
        int b = row >> 9, t = row & 511;                 // b wave-uniform
        int len_b = __shfl(lv, b);
        if (t >= len_b) return;                          // dead row (wave-uniform)
        int crow = __shfl(lx - lv, b) + t;               // offs[b] + t
        size_t src = (size_t)row  * S_ + (threadIdx.x & 127) * 8;
        size_t dst = (size_t)crow * S_ + (threadIdx.x & 127) * 8;
        float4v f0 = __builtin_nontemporal_load((const float4v*)(s + src));
        float4v f1 = __builtin_nontemporal_load((const float4v*)(s + src + 4));
        short8 o;
        o[0] = (short)f2bf(f0[0]); o[1] = (short)f2bf(f0[1]);
        o[2] = (short)f2bf(f0[2]); o[3] = (short)f2bf(f0[3]);
        o[4] = (short)f2bf(f1[0]); o[5] = (short)f2bf(f1[1]);
        o[6] = (short)f2bf(f1[2]); o[7] = (short)f2bf(f1[3]);
        *(short8*)(Sb + dst) = o;
    } else {
        __shared__ float tile[32][33];
        int tb = bid - 16384;
        int h0 = (tb & 127) * 32;                        // H dim
        int k0 = (tb >> 7) * 32;                         // S dim
        int tx = threadIdx.x & 31, ty = threadIdx.x >> 5; // 32 x 8
        for (int r = ty; r < 32; r += 8)
            tile[r][tx] = __builtin_nontemporal_load(&W1[(size_t)(k0 + r) * H_ + h0 + tx]);
        __syncthreads();
        for (int r = ty; r < 32; r += 8)
            W1T[(size_t)(h0 + r) * S_ + k0 + tx] = f2bf(tile[tx][r]);
    }
}

// ---- main fused GEMM: EXACT 287us body + compaction + FUSED logsoftmax ----
// K-loop/epilogue byte-identical to round-6 (schedule axis exhausted, rounds
// 2-5). New: (1) M_live self-computed (offsets kernel deleted); (2) the last
// of the 32 n-blocks per m-tile (tracked via cnt[mtile] atomics) computes the
// log-softmax + masked sum for its 128 rows and accumulates into out --
// removes the reduce_logp dispatch. zbuf is read back with atomicAdd(p,0.f)
// (atomic-read at the atomics' coherence point -> immune to cross-XCD L2
// staleness); release/acquire via __threadfence around the counter.
__global__ __launch_bounds__(256, 3) void gemm_fused_kernel(
        const unsigned short* __restrict__ Sb,    // M_live x S bf16 (compact)
        const unsigned short* __restrict__ W1T,   // H x S bf16
        const float* __restrict__ b1,             // H
        const float* __restrict__ W2,             // H x 32 fp32 (cols 0..3 used)
        const int*   __restrict__ lengths,        // B
        const int*   __restrict__ actions,        // B x MAXT
        const float* __restrict__ b2,             // 32 (cols 0..3 used)
        int*         __restrict__ cnt,            // 256 counters (zeroed)
        float*       __restrict__ zbuf,           // M x 4 (compact rows)
        float*       __restrict__ out)            // scalar accumulator
{
    __shared__ int   lastflag;
    __shared__ int   offs_l[64];
    __shared__ float wsum[4];

    int tid  = threadIdx.x;
    int lane = tid & 63;

    // self-computed M_live (per-wave scan; lengths L2-hot)
    int lv; int lx = wave_scan_len(lengths, lane, lv);
    int M_live = __shfl(lx, 63);

    int id   = blockIdx.x;
    int xcd  = id & 7;
    int slot = id >> 3;                  // 0..1023
    int ntile = xcd * 4 + (slot & 3);    // 0..31
    int mtile = slot >> 2;               // 0..255

    int m0 = mtile * 128;
    if (m0 >= M_live) return;            // beyond compacted rows (uniform)

    int n0 = ntile * 128;

    __shared__ unsigned short smemA[2 * 128 * 32];   // 2 x 8 KB
    __shared__ unsigned short smemB[2 * 128 * 32];   // 2 x 8 KB

    int wid  = tid >> 6;
    int lane15 = lane & 15;
    int quad   = lane >> 4;
    int wave_m = (wid >> 1) * 64;
    int wave_n = (wid & 1) * 64;

    // staging chunk map: chunk c -> row m=c>>2, slot cp=c&3, global k-chunk
    // q = cp ^ ((m>>1)&3)  (XOR swizzle -> 2-way-free LDS access)
    int cA0 = tid, cA1 = tid + 256;
    int mA0 = cA0 >> 2, cp0 = cA0 & 3, q0 = cp0 ^ ((mA0 >> 1) & 3);
    int mA1 = cA1 >> 2, cp1 = cA1 & 3, q1 = cp1 ^ ((mA1 >> 1) & 3);

    const char* gA0 = (const char*)Sb  + (size_t)(m0 + mA0) * (S_*2) + q0 * 16;
    const char* gA1 = (const char*)Sb  + (size_t)(m0 + mA1) * (S_*2) + q1 * 16;
    const char* gB0 = (const char*)W1T + (size_t)(n0 + mA0) * (S_*2) + q0 * 16;
    const char* gB1 = (const char*)W1T + (size_t)(n0 + mA1) * (S_*2) + q1 * 16;
    char* lwA0 = (char*)smemA + cA0 * 16;   // buf0 write addrs; buf1 = +8192
    char* lwA1 = (char*)smemA + cA1 * 16;
    char* lwB0 = (char*)smemB + cA0 * 16;
    char* lwB1 = (char*)smemB + cA1 * 16;

    // fragment read offsets within a buffer (in shorts)
    int aOff[4], bOff[4];
#pragma unroll
    for (int s = 0; s < 4; s++) {
        int ml = wave_m + s * 16 + lane15;
        aOff[s] = ml * 32 + (quad ^ ((ml >> 1) & 3)) * 8;
        int nl = wave_n + s * 16 + lane15;
        bOff[s] = nl * 32 + (quad ^ ((nl >> 1) & 3)) * 8;
    }

    float4v acc[4][4] = {};
    short8 sA0[3], sA1[3], sB0[3], sB1[3];   // 3 register sets -> distance-2 pipeline

    // prologue: issue loads for iters 0,1,2 (constant offsets, monotone vmcnt order)
#pragma unroll
    for (int p = 0; p < 3; p++) {
        sA0[p] = *(const short8*)(gA0 + p * 64);
        sA1[p] = *(const short8*)(gA1 + p * 64);
        sB0[p] = *(const short8*)(gB0 + p * 64);
        sB1[p] = *(const short8*)(gB1 + p * 64);
    }
    // stage iter 0 into buf0 (compiler waits vmcnt only for set 0)
    *(short8*)lwA0 = sA0[0]; *(short8*)lwA1 = sA1[0];
    *(short8*)lwB0 = sB0[0]; *(short8*)lwB1 = sB1[0];

#pragma unroll
    for (int j = 0; j < NITER; j++) {
        __syncthreads();   // buf[j&1] staged (lgkmcnt only -- no global drain)
        // refill the set just consumed: data for iter j+3, in flight for 2 sub-iters
        if (j + 3 < NITER) {
            sA0[j % 3] = *(const short8*)(gA0 + (j + 3) * 64);
            sA1[j % 3] = *(const short8*)(gA1 + (j + 3) * 64);
            sB0[j % 3] = *(const short8*)(gB0 + (j + 3) * 64);
            sB1[j % 3] = *(const short8*)(gB1 + (j + 3) * 64);
        }
        // stage iter j+1 into the other buffer
        if (j + 1 < NITER) {
            int nb = ((j + 1) & 1) * 8192;
            *(short8*)(lwA0 + nb) = sA0[(j + 1) % 3];
            *(short8*)(lwA1 + nb) = sA1[(j + 1) % 3];
            *(short8*)(lwB0 + nb) = sB0[(j + 1) % 3];
            *(short8*)(lwB1 + nb) = sB1[(j + 1) % 3];
        }
        // compute iter j from buf[j&1]
        const unsigned short* aP = smemA + (j & 1) * 4096;
        const unsigned short* bP = smemB + (j & 1) * 4096;
        short8 af[4], bf[4];
#pragma unroll
        for (int s = 0; s < 4; s++) {
            af[s] = *(const short8*)(aP + aOff[s]);
            bf[s] = *(const short8*)(bP + bOff[s]);
        }
#pragma unroll
        for (int i = 0; i < 4; i++)
#pragma unroll
            for (int jj = 0; jj < 4; jj++)
                acc[i][jj] = __builtin_amdgcn_mfma_f32_16x16x32_bf16(af[i], bf[jj], acc[i][jj], 0, 0, 0);
    }

    // ---- fused epilogue: relu(h) @ W2[:,0:4], shuffle-reduce, atomicAdd ----
    float4v w2r[4];
    float   b1v[4];
#pragma unroll
    for (int ns = 0; ns < 4; ns++) {
        int n_g = n0 + wave_n + ns * 16 + lane15;
        w2r[ns] = *(const float4v*)(W2 + (size_t)n_g * 32);
        b1v[ns] = b1[n_g];
    }
#pragma unroll
    for (int ms = 0; ms < 4; ms++) {
        float p[4][4];
#pragma unroll
        for (int r = 0; r < 4; r++)
#pragma unroll
            for (int c = 0; c < 4; c++) p[r][c] = 0.f;
#pragma unroll
        for (int ns = 0; ns < 4; ns++) {
            float4v av = acc[ms][ns];
#pragma unroll
            for (int r = 0; r < 4; r++) {
                float h = av[r] + b1v[ns];
                h = h > 0.f ? h : 0.f;
                p[r][0] += h * w2r[ns][0];
                p[r][1] += h * w2r[ns][1];
                p[r][2] += h * w2r[ns][2];
                p[r][3] += h * w2r[ns][3];
            }
        }
#pragma unroll
        for (int off = 1; off < 16; off <<= 1)
#pragma unroll
            for (int r = 0; r < 4; r++)
#pragma unroll
                for (int c = 0; c < 4; c++)
                    p[r][c] += __shfl_xor(p[r][c], off);
        if (lane15 < 4) {
            int c = lane15;
#pragma unroll
            for (int r = 0; r < 4; r++) {
                int mg = m0 + wave_m + ms * 16 + quad * 4 + r;
                atomicAdd(&zbuf[(size_t)mg * 4 + c], p[r][c]);
            }
        }
    }

    // ---- fused log-softmax reduction: last of 32 n-blocks per m-tile ----
    __syncthreads();                       // all this block's zbuf atomics drained
    if (tid == 0) {
        __threadfence();                   // release
        int old = atomicAdd(&cnt[mtile], 1);
        lastflag = (old == 31);
    }
    __syncthreads();
    if (lastflag) {
        __threadfence();                   // acquire
        if (tid < 64) {                    // rebuild offs in LDS (wave 0)
            int v; int x = wave_scan_len(lengths, tid, v);
            offs_l[tid] = x - v;
        }
        __syncthreads();
        float local = 0.f;
        int crow = m0 + tid;
        if (tid < 128 && crow < M_live) {
            // largest b with offs_l[b] <= crow  (offs_l[0]=0 <= crow)
            int lo = 0;
#pragma unroll
            for (int s = 32; s > 0; s >>= 1) {
                int mid = lo + s;
                if (mid < 64 && offs_l[mid] <= crow) lo = mid;
            }
            int t = crow - offs_l[lo];
            float z0 = atomicAdd(&zbuf[(size_t)crow * 4 + 0], 0.f) + b2[0];
            float z1 = atomicAdd(&zbuf[(size_t)crow * 4 + 1], 0.f) + b2[1];
            float z2 = atomicAdd(&zbuf[(size_t)crow * 4 + 2], 0.f) + b2[2];
            float z3 = atomicAdd(&zbuf[(size_t)crow * 4 + 3], 0.f) + b2[3];
            float mx = fmaxf(fmaxf(z0, z1), fmaxf(z2, z3));
            float se = expf(z0 - mx) + expf(z1 - mx) + expf(z2 - mx) + expf(z3 - mx);
            int a = actions[lo * MAXT + t];
            float za = (a == 0) ? z0 : (a == 1) ? z1 : (a == 2) ? z2 : z3;
            local = (za - mx) - logf(se);
        }
#pragma unroll
        for (int off = 32; off > 0; off >>= 1) local += __shfl_xor(local, off);
        if (lane == 0) wsum[wid] = local;
        __syncthreads();
        if (tid == 0) atomicAdd(out, -(wsum[0] + wsum[1] + wsum[2] + wsum[3]));
    }
}

extern "C" void kernel_launch(void* const* d_in, const int* in_sizes, int n_in,
                              void* d_out, int out_size, void* d_ws, size_t ws_size,
                              hipStream_t stream) {
    const float* s       = (const float*)d_in[0];  // (64,512,1024) fp32
    const int*   actions = (const int*)  d_in[1];  // (64,511)
    const int*   lengths = (const int*)  d_in[2];  // (64,)
    const float* W1      = (const float*)d_in[3];  // (1024,4096)
    const float* b1      = (const float*)d_in[4];  // (4096,)
    const float* W2      = (const float*)d_in[5];  // (4096,32)
    const float* b2      = (const float*)d_in[6];  // (32,)

    char* ws = (char*)d_ws;
    float*          zbuf = (float*)ws;             // [0, 512KB)
    int*            cnt  = (int*)(ws + CNT_OFF);   // 256 counters
    unsigned short* Sb   = (unsigned short*)(ws + SBF_OFF);
    unsigned short* W1T  = (unsigned short*)(ws + W1T_OFF);

    // zero zbuf + counter page and output accumulator (ws/out poisoned 0xAA)
    hipMemsetAsync(ws, 0, ZSCRATCH_BYTES, stream);
    hipMemsetAsync(d_out, 0, sizeof(float), stream);

    // merged pre-pass: s->bf16 compacted rows + W1->W1T bf16 (self-scans offs)
    prep_kernel<<<dim3(16384 + 4096), 256, 0, stream>>>(s, W1, lengths, Sb, W1T);
    // fused GEMM + relu + W2[:,0:4] projection + log-softmax reduction -> out
    gemm_fused_kernel<<<dim3(8192), 256, 0, stream>>>(Sb, W1T, b1, W2, lengths,
                                                      actions, b2, cnt, zbuf,
                                                      (float*)d_out);
}